// Round 15
// baseline (177.542 us; speedup 1.0000x reference)
//
#include <hip/hip_runtime.h>
#include <hip/hip_fp16.h>

typedef unsigned short ushort_t;
typedef __attribute__((ext_vector_type(8))) _Float16 f16x8;
typedef __attribute__((ext_vector_type(2))) _Float16 f16v2;
typedef __attribute__((ext_vector_type(2))) __fp16 hw16x2;
typedef __attribute__((ext_vector_type(4))) float f32x4;

#define BB   2
#define CCH  256
#define HF   96
#define WF   320
#define NYC  7
#define DWT  16384
#define PLANE (HF*WF)          // 30720
#define KDIM (CCH*NYC)         // 1792
#define NKT  56                // K tiles of 32 (k = y*256 + c)
#define MS   8                 // positions per sample block
#define POS_TOTAL (BB*DWT)     // 32768

#define WH_BYTES   ((size_t)16*NKT*64*8*2)          // 917504
#define IITH_BYTES ((size_t)BB*PLANE*CCH*2)         // 31457280

// async global->LDS, 16B per lane (lane-linear dest; per-lane global src)
__device__ __forceinline__ void glds16(const void* gsrc, void* lds) {
    __builtin_amdgcn_global_load_lds(
        (const __attribute__((address_space(1))) unsigned int*)gsrc,
        (__attribute__((address_space(3))) unsigned int*)lds, 16, 0, 0);
}

// ---------------- K1: fused integral image (rowcum + colcum) -----------------
__global__ __launch_bounds__(512)
void k_integral(const float* __restrict__ f, float* __restrict__ ii) {
    __shared__ float pl[PLANE];            // 122880 B
    int bc = blockIdx.x;
    const float* src = f  + (size_t)bc * PLANE;
    float*       dst = ii + (size_t)bc * PLANE;
    int t = threadIdx.x;

    #pragma unroll
    for (int i = 0; i < PLANE / 4 / 512; ++i) {
        int idx = t + i * 512;
        reinterpret_cast<float4*>(pl)[idx] = reinterpret_cast<const float4*>(src)[idx];
    }
    __syncthreads();

    int lane = t & 63, wv = t >> 6;
    for (int rr = 0; rr < 12; ++rr) {
        float* row = &pl[(wv * 12 + rr) * WF];
        float v0 = row[lane * 5 + 0];
        float v1 = row[lane * 5 + 1];
        float v2 = row[lane * 5 + 2];
        float v3 = row[lane * 5 + 3];
        float v4 = row[lane * 5 + 4];
        v1 += v0; v2 += v1; v3 += v2; v4 += v3;
        float s = v4;
        #pragma unroll
        for (int d = 1; d < 64; d <<= 1) {
            float o = __shfl_up(s, d);
            if (lane >= d) s += o;
        }
        float pre = s - v4;
        row[lane * 5 + 0] = v0 + pre;
        row[lane * 5 + 1] = v1 + pre;
        row[lane * 5 + 2] = v2 + pre;
        row[lane * 5 + 3] = v3 + pre;
        row[lane * 5 + 4] = v4 + pre;
    }
    __syncthreads();

    if (t < WF) {
        int x = t;
        float acc = 0.f;
        #pragma unroll 4
        for (int y = 0; y < HF; ++y) {
            acc += pl[y * WF + x];
            dst[(size_t)y * WF + x] = acc;
        }
    }
}

// ---------------- K2: transpose ii (B,C,H,W) f32 -> iith (B,H,W,C) fp16 ------
__global__ void k_transpose(const float* __restrict__ ii, _Float16* __restrict__ iith) {
    __shared__ float tile[32][33];
    int x0 = blockIdx.x * 32;
    int c0 = blockIdx.y * 32;
    int by = blockIdx.z;               // b*HF + y
    int b  = by / HF;
    int y  = by % HF;
    const float* src = ii + (size_t)b * CCH * PLANE + (size_t)y * WF;
    unsigned* dstu = reinterpret_cast<unsigned*>(iith + (size_t)by * WF * CCH);
    int tx = threadIdx.x;
    int ty = threadIdx.y;
    #pragma unroll
    for (int i = 0; i < 4; ++i) {
        int c = c0 + ty + 8 * i;
        tile[ty + 8 * i][tx] = src[(size_t)c * PLANE + x0 + tx];
    }
    __syncthreads();
    int id = ty * 32 + tx;
    #pragma unroll
    for (int it = 0; it < 2; ++it) {
        int idx = it * 256 + id;
        int xl = idx >> 4;
        int j  = idx & 15;
        float f0 = tile[2 * j][xl];
        float f1 = tile[2 * j + 1][xl];
        __half2 hh = __floats2half2_rn(f0, f1);
        dstu[((size_t)(x0 + xl) * CCH + c0) / 2 + j] = *reinterpret_cast<unsigned*>(&hh);
    }
}

// ---------------- K3: geometry -> g_tl, g_br, g_tr, g_bl ----------------
__global__ void k_geom(const float* __restrict__ calib, const float* __restrict__ grid,
                       float* __restrict__ gtl, float* __restrict__ gbr,
                       float* __restrict__ gtr, float* __restrict__ gbl) {
    int t = blockIdx.x * blockDim.x + threadIdx.x;
    if (t >= BB * NYC * DWT) return;
    int dw = t % DWT;
    int by = t / DWT;
    int y  = by % NYC;
    int b  = by / NYC;
    int d  = dw >> 7;
    int w  = dw & 127;
    const float* cb = calib + b * 12;

    float c0=cb[0],c1=cb[1],c2=cb[2],c3=cb[3];
    float c4=cb[4],c5=cb[5],c6=cb[6],c7=cb[7];
    float c8=cb[8],c9=cb[9],c10=cb[10],c11=cb[11];

    auto ncp = [&](int yy, int i, int j, float& ox, float& oy) {
        const float* g = grid + (((size_t)b * 129 + i) * 129 + j) * 3;
        float gx = g[0];
        float gy = g[1] + (0.5f * (float)yy - 2.0f);
        float gz = g[2];
        float h0 = c0*gx + c1*gy + c2*gz + c3;
        float h1 = c4*gx + c5*gy + c6*gz + c7;
        float h2 = c8*gx + c9*gy + c10*gz + c11;
        float ix = h0 / h2;
        float iy = h1 / h2;
        float nx = 2.0f * ix / ((float)WF / 0.125f) - 1.0f;
        float ny = 2.0f * iy / ((float)HF / 0.125f) - 1.0f;
        ox = fminf(fmaxf(nx, -1.f), 1.f);
        oy = fminf(fmaxf(ny, -1.f), 1.f);
    };

    float ax, ay, bx, byy, mx1, my1, mx2, my2;
    ncp(y,     d,     w,     ax,  ay);
    ncp(y,     d + 1, w,     bx,  byy);
    float minx = fminf(ax, bx), miny = fminf(ay, byy);
    ncp(y + 1, d + 1, w + 1, mx1, my1);
    ncp(y + 1, d,     w + 1, mx2, my2);
    float maxx = fmaxf(mx1, mx2), maxy = fmaxf(my1, my2);

    size_t o = (size_t)t * 2;
    gtl[o] = minx; gtl[o + 1] = miny;
    gbr[o] = maxx; gbr[o + 1] = maxy;
    gtr[o] = maxx; gtr[o + 1] = miny;
    gbl[o] = minx; gbl[o + 1] = maxy;
}

// ---------------- K4: prepack w -> fragment-linear f16 (k = y*256 + c) -------
__global__ void k_prepack(const float* __restrict__ w, _Float16* __restrict__ wh) {
    int t = blockIdx.x * blockDim.x + threadIdx.x;
    if (t >= 16 * NKT * 64) return;
    int lane = t & 63;
    int kt   = (t >> 6) % NKT;
    int nt   = t / (NKT * 64);
    int r = lane & 15, g = lane >> 4;
    const float* wr = w + (size_t)(nt * 16 + r) * KDIM;
    _Float16* dst = wh + (size_t)t * 8;
    #pragma unroll
    for (int j = 0; j < 8; ++j) {
        int k  = kt * 32 + g * 8 + j;
        int yy = k >> 8;
        int cc = k & 255;
        dst[j] = (_Float16)wr[cc * NYC + yy];
    }
}

// ---------------- K5: pure gather -> vox fragments (f16) ---------------------
// thread: p = t>>5 (8 positions/block), c = (t&31)*8 (channel octet)
__global__ __launch_bounds__(256, 4)
void k_sample(const _Float16* __restrict__ iith, const float* __restrict__ gtl,
              const float* __restrict__ gbr, _Float16* __restrict__ voxf, int pos_base) {
    __shared__ int2 taps[MS][NYC][17];       // 17-pad
    __shared__ float inv_s[MS][NYC + 1];
    int t = threadIdx.x;
    int bid = blockIdx.x;
    int cpx = gridDim.x >> 3;
    int swz = (bid & 7) * cpx + (bid >> 3);  // XCD-chunked (grid % 8 == 0)
    int lpos0 = swz * MS;
    int pos0  = pos_base + lpos0;
    int b   = pos0 / DWT;
    int dw0 = pos0 % DWT;

    if (t < MS * NYC) {
        int p = t / NYC, y = t % NYC;
        size_t gi = (((size_t)(b * NYC + y)) * DWT + dw0 + p) * 2;
        float g0 = gtl[gi], g1 = gtl[gi + 1];
        float g2 = gbr[gi], g3 = gbr[gi + 1];
        float area = (g2 - g0) * (g3 - g1) * ((float)HF * (float)WF * 0.25f) + 1e-6f;
        inv_s[p][y] = (area > 1e-6f) ? (1.0f / area) : 0.0f;
        const float sgn[4] = {1.f, 1.f, -1.f, -1.f};
        float px[4] = {g0, g2, g2, g0};
        float py[4] = {g1, g3, g1, g3};
        #pragma unroll
        for (int q = 0; q < 4; ++q) {
            float x  = (px[q] + 1.0f) * ((float)WF * 0.5f) - 0.5f;
            float yy = (py[q] + 1.0f) * ((float)HF * 0.5f) - 0.5f;
            float x0f = floorf(x), y0f = floorf(yy);
            float wx = x - x0f, wy = yy - y0f;
            float wq[4] = {(1.f-wx)*(1.f-wy), wx*(1.f-wy), (1.f-wx)*wy, wx*wy};
            #pragma unroll
            for (int s = 0; s < 4; ++s) {
                float xi = x0f + (float)(s & 1);
                float yi = y0f + (float)(s >> 1);
                bool valid = (xi >= 0.f) && (xi < (float)WF) && (yi >= 0.f) && (yi < (float)HF);
                int xc = (int)fminf(fmaxf(xi, 0.f), (float)(WF - 1));
                int yc = (int)fminf(fmaxf(yi, 0.f), (float)(HF - 1));
                float wgt = valid ? (wq[s] * sgn[q]) : 0.0f;
                hw16x2 hw = __builtin_amdgcn_cvt_pkrtz(wgt, wgt);
                taps[p][y][q * 4 + s] =
                    make_int2((yc * WF + xc) * CCH, *reinterpret_cast<int*>(&hw));
            }
        }
    }
    __syncthreads();

    int p = t >> 5;
    int c = (t & 31) * 8;
    int lpos = lpos0 + p;
    int mt = lpos >> 4, r = lpos & 15, g = (c >> 3) & 3;
    const _Float16* base = iith + (size_t)b * PLANE * CCH + c;
    _Float16* vbase = voxf + ((size_t)mt * NKT * 64 + (size_t)(g * 16 + r)) * 8;

    for (int y = 0; y < NYC; ++y) {
        int2 tp[16];
        #pragma unroll
        for (int q = 0; q < 16; ++q) tp[q] = taps[p][y][q];

        uint4 hv[16];
        #pragma unroll
        for (int q = 0; q < 16; ++q)
            hv[q] = *reinterpret_cast<const uint4*>(base + tp[q].x);
        __builtin_amdgcn_sched_barrier(0);

        f16v2 a0 = {0, 0}, a1 = {0, 0}, a2 = {0, 0}, a3 = {0, 0};
        #pragma unroll
        for (int q = 0; q < 16; ++q) {
            f16v2 w2 = *reinterpret_cast<f16v2*>(&tp[q].y);
            a0 += w2 * *reinterpret_cast<f16v2*>(&hv[q].x);
            a1 += w2 * *reinterpret_cast<f16v2*>(&hv[q].y);
            a2 += w2 * *reinterpret_cast<f16v2*>(&hv[q].z);
            a3 += w2 * *reinterpret_cast<f16v2*>(&hv[q].w);
        }
        float inv = inv_s[p][y];
        hw16x2 ivh = __builtin_amdgcn_cvt_pkrtz(inv, inv);
        f16v2 iv2 = *reinterpret_cast<f16v2*>(&ivh);
        a0 *= iv2; a1 *= iv2; a2 *= iv2; a3 *= iv2;

        int kt = (y << 3) + (c >> 5);
        f16x8 o;
        o[0] = a0[0]; o[1] = a0[1]; o[2] = a1[0]; o[3] = a1[1];
        o[4] = a2[0]; o[5] = a2[1]; o[6] = a3[0]; o[7] = a3[1];
        // normal cached store (r10: nontemporal doubles HBM writes)
        *reinterpret_cast<f16x8*>(vbase + (size_t)kt * 64 * 8) = o;
    }
}

// ---------------- K6: MFMA GEMM with async LDS-staged A ----------------------
// 128M x 128N per block, 4 waves (2x2). A staged via global_load_lds (8KB/kt,
// double-buffered); B register-direct depth-2. A read once per block (was 2x).
__global__ __launch_bounds__(256, 3)
void k_gemm(const _Float16* __restrict__ voxf, const _Float16* __restrict__ wh,
            const float* __restrict__ bias, float* __restrict__ ortho, int pos_base) {
    __shared__ f16x8 A_lds[2][8 * 64];      // 16384 B
    int t = threadIdx.x;
    int lane = t & 63, wv = t >> 6;
    int mi = wv >> 1, ni = wv & 1;
    int bx = blockIdx.x;
    int swz = (bx & 7) * (gridDim.x >> 3) + (bx >> 3);   // XCD-chunked
    int nhalf = swz & 1, pm = swz >> 1;
    int lpos0 = pm * 128;
    int pos0 = pos_base + lpos0;
    int b = pos0 / DWT, dw0 = pos0 % DWT;
    int mt0 = lpos0 >> 4;
    int nt0 = nhalf * 8 + ni * 4;

    const char* abase = (const char*)voxf;
    const f16x8* bp = reinterpret_cast<const f16x8*>(wh) + (size_t)nt0 * NKT * 64 + lane;
    const size_t TS = (size_t)NKT * 64;     // tile stride in f16x8

    // stage A-tile for k-step kt into buf: 8 chunks of 1KB; wave wv does 2
    auto stageA = [&](int kt, int buf) {
        #pragma unroll
        for (int i = 0; i < 2; ++i) {
            int mt = wv * 2 + i;
            const char* gsrc = abase + (((size_t)(mt0 + mt) * NKT + kt) * 64 * 16)
                             + (size_t)lane * 16;
            glds16(gsrc, &A_lds[buf][mt * 64]);
        }
    };

    f32x4 acc[4][4] = {};
    f16x8 Bc[4], Bn[4];
    #pragma unroll
    for (int i = 0; i < 4; ++i) Bc[i] = bp[i * TS];

    stageA(0, 0);
    __syncthreads();                        // drains vmcnt -> buf0 ready

    int buf = 0;
    for (int kt = 0; kt < NKT; ++kt) {
        if (kt + 1 < NKT) {
            stageA(kt + 1, buf ^ 1);        // async, flies under the MFMAs
            #pragma unroll
            for (int i = 0; i < 4; ++i) Bn[i] = bp[i * TS + (size_t)(kt + 1) * 64];
        }
        f16x8 Af[4];
        #pragma unroll
        for (int m = 0; m < 4; ++m) Af[m] = A_lds[buf][(mi * 4 + m) * 64 + lane];
        #pragma unroll
        for (int m = 0; m < 4; ++m)
            #pragma unroll
            for (int n = 0; n < 4; ++n)
                acc[m][n] = __builtin_amdgcn_mfma_f32_16x16x32_f16(Af[m], Bc[n], acc[m][n], 0, 0, 0);
        #pragma unroll
        for (int i = 0; i < 4; ++i) Bc[i] = Bn[i];
        __syncthreads();                    // next buf fully written; cur buf free
        buf ^= 1;
    }

    int r = lane & 15, gq = lane >> 4;
    #pragma unroll
    for (int n = 0; n < 4; ++n) {
        int co = nhalf * 128 + (ni * 4 + n) * 16 + r;
        float bv = bias[co];
        float* ob = ortho + ((size_t)(b * CCH + co)) * DWT + dw0 + gq * 4;
        #pragma unroll
        for (int m = 0; m < 4; ++m) {
            float4 o = make_float4(fmaxf(acc[m][n][0] + bv, 0.f), fmaxf(acc[m][n][1] + bv, 0.f),
                                   fmaxf(acc[m][n][2] + bv, 0.f), fmaxf(acc[m][n][3] + bv, 0.f));
            *reinterpret_cast<float4*>(ob + (mi * 4 + m) * 16) = o;
        }
    }
}

extern "C" void kernel_launch(void* const* d_in, const int* in_sizes, int n_in,
                              void* d_out, int out_size, void* d_ws, size_t ws_size,
                              hipStream_t stream) {
    const float* features = (const float*)d_in[0];
    const float* calib    = (const float*)d_in[1];
    const float* grid     = (const float*)d_in[2];
    const float* w        = (const float*)d_in[3];
    const float* bias     = (const float*)d_in[4];

    float* out   = (float*)d_out;
    float* ortho = out;
    float* ii    = out + (size_t)8388608;
    float* gtl   = out + (size_t)24117248;
    float* gbr   = out + (size_t)24576000;
    float* gtr   = out + (size_t)25034752;
    float* gbl   = out + (size_t)25493504;

    _Float16* wh   = (_Float16*)d_ws;
    _Float16* iith = (_Float16*)((char*)d_ws + WH_BYTES);
    _Float16* voxf = (_Float16*)((char*)d_ws + WH_BYTES + IITH_BYTES);

    k_integral<<<BB * CCH, 512, 0, stream>>>(features, ii);
    k_geom    <<<(BB * NYC * DWT + 255) / 256, 256, 0, stream>>>(calib, grid, gtl, gbr, gtr, gbl);
    k_prepack <<<(16 * NKT * 64 + 255) / 256, 256, 0, stream>>>(w, wh);
    dim3 gT(WF / 32, CCH / 32, BB * HF);
    k_transpose<<<gT, dim3(32, 8), 0, stream>>>(ii, iith);

    // nch=1 when ws fits the full vox (117 MB)
    size_t vox_all = (size_t)POS_TOTAL * KDIM * 2;
    int nch = (ws_size >= WH_BYTES + IITH_BYTES + vox_all) ? 1 : 4;
    int cpos = POS_TOTAL / nch;
    for (int cidx = 0; cidx < nch; ++cidx) {
        int pb = cidx * cpos;
        k_sample<<<cpos / MS, 256, 0, stream>>>(iith, gtl, gbr, voxf, pb);
        k_gemm  <<<(cpos / 128) * 2, 256, 0, stream>>>(voxf, wh, bias, ortho, pb);
    }
}

// Round 16
// 175.567 us; speedup vs baseline: 1.0112x; 1.0112x over previous
//
#include <hip/hip_runtime.h>
#include <hip/hip_fp16.h>

typedef unsigned short ushort_t;
typedef __attribute__((ext_vector_type(8))) _Float16 f16x8;
typedef __attribute__((ext_vector_type(2))) _Float16 f16v2;
typedef __attribute__((ext_vector_type(2))) __fp16 hw16x2;
typedef __attribute__((ext_vector_type(4))) float f32x4;

#define BB   2
#define CCH  256
#define HF   96
#define WF   320
#define NYC  7
#define DWT  16384
#define PLANE (HF*WF)          // 30720
#define KDIM (CCH*NYC)         // 1792
#define NKT  56                // K tiles of 32 (k = y*256 + c)
#define MS   8                 // positions per sample block
#define POS_TOTAL (BB*DWT)     // 32768

#define WH_BYTES   ((size_t)16*NKT*64*8*2)          // 917504
#define IITH_BYTES ((size_t)BB*PLANE*CCH*2)         // 31457280

// ---------------- K1: fused integral image, split column scan ---------------
// 640 threads: rows over 10 waves; columns split y<48 / y>=48 (parallel chains)
__global__ __launch_bounds__(640)
void k_integral(const float* __restrict__ f, float* __restrict__ ii) {
    __shared__ float pl[PLANE];            // 122880 B
    __shared__ float tot[WF];              // 1280 B
    int bc = blockIdx.x;
    const float* src = f  + (size_t)bc * PLANE;
    float*       dst = ii + (size_t)bc * PLANE;
    int t = threadIdx.x;

    #pragma unroll
    for (int i = 0; i < PLANE / 4 / 640; ++i) {      // 12 iters exact
        int idx = t + i * 640;
        reinterpret_cast<float4*>(pl)[idx] = reinterpret_cast<const float4*>(src)[idx];
    }
    __syncthreads();

    int lane = t & 63, wv = t >> 6;                  // 10 waves
    for (int rr = wv; rr < HF; rr += 10) {
        float* row = &pl[rr * WF];
        float v0 = row[lane * 5 + 0];
        float v1 = row[lane * 5 + 1];
        float v2 = row[lane * 5 + 2];
        float v3 = row[lane * 5 + 3];
        float v4 = row[lane * 5 + 4];
        v1 += v0; v2 += v1; v3 += v2; v4 += v3;
        float s = v4;
        #pragma unroll
        for (int d = 1; d < 64; d <<= 1) {
            float o = __shfl_up(s, d);
            if (lane >= d) s += o;
        }
        float pre = s - v4;
        row[lane * 5 + 0] = v0 + pre;
        row[lane * 5 + 1] = v1 + pre;
        row[lane * 5 + 2] = v2 + pre;
        row[lane * 5 + 3] = v3 + pre;
        row[lane * 5 + 4] = v4 + pre;
    }
    __syncthreads();

    // column scan: two 48-long chains in parallel
    bool lower = t < WF;
    int x = lower ? t : t - WF;
    float loc[48];
    if (lower) {
        float acc = 0.f;
        #pragma unroll 4
        for (int y = 0; y < 48; ++y) {
            acc += pl[y * WF + x];
            dst[(size_t)y * WF + x] = acc;
        }
        tot[x] = acc;
    } else {
        float acc = 0.f;
        #pragma unroll
        for (int y = 0; y < 48; ++y) {
            acc += pl[(48 + y) * WF + x];
            loc[y] = acc;
        }
    }
    __syncthreads();
    if (!lower) {
        float base = tot[x];
        #pragma unroll
        for (int y = 0; y < 48; ++y)
            dst[(size_t)(48 + y) * WF + x] = loc[y] + base;
    }
}

// ---------------- K2: transpose ii (B,C,H,W) f32 -> iith (B,H,W,C) fp16 ------
__global__ void k_transpose(const float* __restrict__ ii, _Float16* __restrict__ iith) {
    __shared__ float tile[32][33];
    int x0 = blockIdx.x * 32;
    int c0 = blockIdx.y * 32;
    int by = blockIdx.z;               // b*HF + y
    int b  = by / HF;
    int y  = by % HF;
    const float* src = ii + (size_t)b * CCH * PLANE + (size_t)y * WF;
    unsigned* dstu = reinterpret_cast<unsigned*>(iith + (size_t)by * WF * CCH);
    int tx = threadIdx.x;
    int ty = threadIdx.y;
    #pragma unroll
    for (int i = 0; i < 4; ++i) {
        int c = c0 + ty + 8 * i;
        tile[ty + 8 * i][tx] = src[(size_t)c * PLANE + x0 + tx];
    }
    __syncthreads();
    int id = ty * 32 + tx;
    #pragma unroll
    for (int it = 0; it < 2; ++it) {
        int idx = it * 256 + id;
        int xl = idx >> 4;
        int j  = idx & 15;
        float f0 = tile[2 * j][xl];
        float f1 = tile[2 * j + 1][xl];
        __half2 hh = __floats2half2_rn(f0, f1);
        dstu[((size_t)(x0 + xl) * CCH + c0) / 2 + j] = *reinterpret_cast<unsigned*>(&hh);
    }
}

// ---------------- K3: geometry -> g_tl, g_br, g_tr, g_bl ----------------
__global__ void k_geom(const float* __restrict__ calib, const float* __restrict__ grid,
                       float* __restrict__ gtl, float* __restrict__ gbr,
                       float* __restrict__ gtr, float* __restrict__ gbl) {
    int t = blockIdx.x * blockDim.x + threadIdx.x;
    if (t >= BB * NYC * DWT) return;
    int dw = t % DWT;
    int by = t / DWT;
    int y  = by % NYC;
    int b  = by / NYC;
    int d  = dw >> 7;
    int w  = dw & 127;
    const float* cb = calib + b * 12;

    float c0=cb[0],c1=cb[1],c2=cb[2],c3=cb[3];
    float c4=cb[4],c5=cb[5],c6=cb[6],c7=cb[7];
    float c8=cb[8],c9=cb[9],c10=cb[10],c11=cb[11];

    auto ncp = [&](int yy, int i, int j, float& ox, float& oy) {
        const float* g = grid + (((size_t)b * 129 + i) * 129 + j) * 3;
        float gx = g[0];
        float gy = g[1] + (0.5f * (float)yy - 2.0f);
        float gz = g[2];
        float h0 = c0*gx + c1*gy + c2*gz + c3;
        float h1 = c4*gx + c5*gy + c6*gz + c7;
        float h2 = c8*gx + c9*gy + c10*gz + c11;
        float ix = h0 / h2;
        float iy = h1 / h2;
        float nx = 2.0f * ix / ((float)WF / 0.125f) - 1.0f;
        float ny = 2.0f * iy / ((float)HF / 0.125f) - 1.0f;
        ox = fminf(fmaxf(nx, -1.f), 1.f);
        oy = fminf(fmaxf(ny, -1.f), 1.f);
    };

    float ax, ay, bx, byy, mx1, my1, mx2, my2;
    ncp(y,     d,     w,     ax,  ay);
    ncp(y,     d + 1, w,     bx,  byy);
    float minx = fminf(ax, bx), miny = fminf(ay, byy);
    ncp(y + 1, d + 1, w + 1, mx1, my1);
    ncp(y + 1, d,     w + 1, mx2, my2);
    float maxx = fmaxf(mx1, mx2), maxy = fmaxf(my1, my2);

    size_t o = (size_t)t * 2;
    gtl[o] = minx; gtl[o + 1] = miny;
    gbr[o] = maxx; gbr[o + 1] = maxy;
    gtr[o] = maxx; gtr[o + 1] = miny;
    gbl[o] = minx; gbl[o + 1] = maxy;
}

// ---------------- K4: prepack w -> fragment-linear f16 (k = y*256 + c) -------
__global__ void k_prepack(const float* __restrict__ w, _Float16* __restrict__ wh) {
    int t = blockIdx.x * blockDim.x + threadIdx.x;
    if (t >= 16 * NKT * 64) return;
    int lane = t & 63;
    int kt   = (t >> 6) % NKT;
    int nt   = t / (NKT * 64);
    int r = lane & 15, g = lane >> 4;
    const float* wr = w + (size_t)(nt * 16 + r) * KDIM;
    _Float16* dst = wh + (size_t)t * 8;
    #pragma unroll
    for (int j = 0; j < 8; ++j) {
        int k  = kt * 32 + g * 8 + j;
        int yy = k >> 8;
        int cc = k & 255;
        dst[j] = (_Float16)wr[cc * NYC + yy];
    }
}

// ---------------- K5: pure gather -> vox fragments (f16) ---------------------
// thread: p = t>>5 (8 positions/block), c = (t&31)*8 (channel octet)
__global__ __launch_bounds__(256, 4)
void k_sample(const _Float16* __restrict__ iith, const float* __restrict__ gtl,
              const float* __restrict__ gbr, _Float16* __restrict__ voxf, int pos_base) {
    __shared__ int2 taps[MS][NYC][17];       // 17-pad
    __shared__ float inv_s[MS][NYC + 1];
    int t = threadIdx.x;
    int bid = blockIdx.x;
    int cpx = gridDim.x >> 3;
    int swz = (bid & 7) * cpx + (bid >> 3);  // XCD-chunked (grid % 8 == 0)
    int lpos0 = swz * MS;
    int pos0  = pos_base + lpos0;
    int b   = pos0 / DWT;
    int dw0 = pos0 % DWT;

    if (t < MS * NYC) {
        int p = t / NYC, y = t % NYC;
        size_t gi = (((size_t)(b * NYC + y)) * DWT + dw0 + p) * 2;
        float g0 = gtl[gi], g1 = gtl[gi + 1];
        float g2 = gbr[gi], g3 = gbr[gi + 1];
        float area = (g2 - g0) * (g3 - g1) * ((float)HF * (float)WF * 0.25f) + 1e-6f;
        inv_s[p][y] = (area > 1e-6f) ? (1.0f / area) : 0.0f;
        const float sgn[4] = {1.f, 1.f, -1.f, -1.f};
        float px[4] = {g0, g2, g2, g0};
        float py[4] = {g1, g3, g1, g3};
        #pragma unroll
        for (int q = 0; q < 4; ++q) {
            float x  = (px[q] + 1.0f) * ((float)WF * 0.5f) - 0.5f;
            float yy = (py[q] + 1.0f) * ((float)HF * 0.5f) - 0.5f;
            float x0f = floorf(x), y0f = floorf(yy);
            float wx = x - x0f, wy = yy - y0f;
            float wq[4] = {(1.f-wx)*(1.f-wy), wx*(1.f-wy), (1.f-wx)*wy, wx*wy};
            #pragma unroll
            for (int s = 0; s < 4; ++s) {
                float xi = x0f + (float)(s & 1);
                float yi = y0f + (float)(s >> 1);
                bool valid = (xi >= 0.f) && (xi < (float)WF) && (yi >= 0.f) && (yi < (float)HF);
                int xc = (int)fminf(fmaxf(xi, 0.f), (float)(WF - 1));
                int yc = (int)fminf(fmaxf(yi, 0.f), (float)(HF - 1));
                float wgt = valid ? (wq[s] * sgn[q]) : 0.0f;
                hw16x2 hw = __builtin_amdgcn_cvt_pkrtz(wgt, wgt);
                taps[p][y][q * 4 + s] =
                    make_int2((yc * WF + xc) * CCH, *reinterpret_cast<int*>(&hw));
            }
        }
    }
    __syncthreads();

    int p = t >> 5;
    int c = (t & 31) * 8;
    int lpos = lpos0 + p;
    int mt = lpos >> 4, r = lpos & 15, g = (c >> 3) & 3;
    const _Float16* base = iith + (size_t)b * PLANE * CCH + c;
    _Float16* vbase = voxf + ((size_t)mt * NKT * 64 + (size_t)(g * 16 + r)) * 8;

    for (int y = 0; y < NYC; ++y) {
        int2 tp[16];
        #pragma unroll
        for (int q = 0; q < 16; ++q) tp[q] = taps[p][y][q];

        uint4 hv[16];
        #pragma unroll
        for (int q = 0; q < 16; ++q)
            hv[q] = *reinterpret_cast<const uint4*>(base + tp[q].x);
        __builtin_amdgcn_sched_barrier(0);

        f16v2 a0 = {0, 0}, a1 = {0, 0}, a2 = {0, 0}, a3 = {0, 0};
        #pragma unroll
        for (int q = 0; q < 16; ++q) {
            f16v2 w2 = *reinterpret_cast<f16v2*>(&tp[q].y);
            a0 += w2 * *reinterpret_cast<f16v2*>(&hv[q].x);
            a1 += w2 * *reinterpret_cast<f16v2*>(&hv[q].y);
            a2 += w2 * *reinterpret_cast<f16v2*>(&hv[q].z);
            a3 += w2 * *reinterpret_cast<f16v2*>(&hv[q].w);
        }
        float inv = inv_s[p][y];
        hw16x2 ivh = __builtin_amdgcn_cvt_pkrtz(inv, inv);
        f16v2 iv2 = *reinterpret_cast<f16v2*>(&ivh);
        a0 *= iv2; a1 *= iv2; a2 *= iv2; a3 *= iv2;

        int kt = (y << 3) + (c >> 5);
        f16x8 o;
        o[0] = a0[0]; o[1] = a0[1]; o[2] = a1[0]; o[3] = a1[1];
        o[4] = a2[0]; o[5] = a2[1]; o[6] = a3[0]; o[7] = a3[1];
        // normal cached store (r10: nontemporal doubles HBM writes)
        *reinterpret_cast<f16x8*>(vbase + (size_t)kt * 64 * 8) = o;
    }
}

// ---------------- K6: register-blocked MFMA GEMM, depth-4 prefetch -----------
// 128M x 128N per block, 4 waves (2x2); wave tile mA=4 x nB=4.
// Grid-limited to 2 waves/SIMD -> deepen per-wave prefetch to 4 k-steps.
__global__ __launch_bounds__(256, 2)
void k_gemm(const _Float16* __restrict__ voxf, const _Float16* __restrict__ wh,
            const float* __restrict__ bias, float* __restrict__ ortho, int pos_base) {
    int t = threadIdx.x;
    int lane = t & 63, wv = t >> 6;
    int mi = wv >> 1, ni = wv & 1;
    int bx = blockIdx.x;
    int swz = (bx & 7) * (gridDim.x >> 3) + (bx >> 3);   // XCD-chunked
    int nhalf = swz & 1, pm = swz >> 1;
    int lpos0 = pm * 128;
    int pos0 = pos_base + lpos0;
    int b = pos0 / DWT, dw0 = pos0 % DWT;
    int mt0 = (lpos0 >> 4) + mi * 4;
    int nt0 = nhalf * 8 + ni * 4;

    const f16x8* ap = reinterpret_cast<const f16x8*>(voxf) + (size_t)mt0 * NKT * 64 + lane;
    const f16x8* bp = reinterpret_cast<const f16x8*>(wh)   + (size_t)nt0 * NKT * 64 + lane;
    const size_t TS = (size_t)NKT * 64;     // tile stride in f16x8

    f32x4 acc[4][4] = {};
    f16x8 A0[4], A1[4], A2[4], A3[4];
    f16x8 B0[4], B1[4], B2[4], B3[4];
    #pragma unroll
    for (int i = 0; i < 4; ++i) {
        A0[i] = ap[i * TS];            B0[i] = bp[i * TS];
        A1[i] = ap[i * TS + 64];       B1[i] = bp[i * TS + 64];
        A2[i] = ap[i * TS + 128];      B2[i] = bp[i * TS + 128];
        A3[i] = ap[i * TS + 192];      B3[i] = bp[i * TS + 192];
    }

#define GSTEP(AJ, BJ, J)                                                        \
    {                                                                           \
        _Pragma("unroll")                                                       \
        for (int m = 0; m < 4; ++m)                                             \
            _Pragma("unroll")                                                   \
            for (int n = 0; n < 4; ++n)                                         \
                acc[m][n] = __builtin_amdgcn_mfma_f32_16x16x32_f16(AJ[m], BJ[n], acc[m][n], 0, 0, 0); \
        int kp = kt + 4 + J; if (kp > NKT - 1) kp = NKT - 1;                    \
        _Pragma("unroll")                                                       \
        for (int i = 0; i < 4; ++i) {                                           \
            AJ[i] = ap[i * TS + (size_t)kp * 64];                               \
            BJ[i] = bp[i * TS + (size_t)kp * 64];                               \
        }                                                                       \
    }

    for (int kt = 0; kt < NKT; kt += 4) {
        GSTEP(A0, B0, 0)
        GSTEP(A1, B1, 1)
        GSTEP(A2, B2, 2)
        GSTEP(A3, B3, 3)
    }
#undef GSTEP

    int r = lane & 15, gq = lane >> 4;
    #pragma unroll
    for (int n = 0; n < 4; ++n) {
        int co = nhalf * 128 + (ni * 4 + n) * 16 + r;
        float bv = bias[co];
        float* ob = ortho + ((size_t)(b * CCH + co)) * DWT + dw0 + gq * 4;
        #pragma unroll
        for (int m = 0; m < 4; ++m) {
            float4 o = make_float4(fmaxf(acc[m][n][0] + bv, 0.f), fmaxf(acc[m][n][1] + bv, 0.f),
                                   fmaxf(acc[m][n][2] + bv, 0.f), fmaxf(acc[m][n][3] + bv, 0.f));
            *reinterpret_cast<float4*>(ob + (mi * 4 + m) * 16) = o;
        }
    }
}

extern "C" void kernel_launch(void* const* d_in, const int* in_sizes, int n_in,
                              void* d_out, int out_size, void* d_ws, size_t ws_size,
                              hipStream_t stream) {
    const float* features = (const float*)d_in[0];
    const float* calib    = (const float*)d_in[1];
    const float* grid     = (const float*)d_in[2];
    const float* w        = (const float*)d_in[3];
    const float* bias     = (const float*)d_in[4];

    float* out   = (float*)d_out;
    float* ortho = out;
    float* ii    = out + (size_t)8388608;
    float* gtl   = out + (size_t)24117248;
    float* gbr   = out + (size_t)24576000;
    float* gtr   = out + (size_t)25034752;
    float* gbl   = out + (size_t)25493504;

    _Float16* wh   = (_Float16*)d_ws;
    _Float16* iith = (_Float16*)((char*)d_ws + WH_BYTES);
    _Float16* voxf = (_Float16*)((char*)d_ws + WH_BYTES + IITH_BYTES);

    k_integral<<<BB * CCH, 640, 0, stream>>>(features, ii);
    k_geom    <<<(BB * NYC * DWT + 255) / 256, 256, 0, stream>>>(calib, grid, gtl, gbr, gtr, gbl);
    k_prepack <<<(16 * NKT * 64 + 255) / 256, 256, 0, stream>>>(w, wh);
    dim3 gT(WF / 32, CCH / 32, BB * HF);
    k_transpose<<<gT, dim3(32, 8), 0, stream>>>(ii, iith);

    // nch=1 when ws fits the full vox (117 MB)
    size_t vox_all = (size_t)POS_TOTAL * KDIM * 2;
    int nch = (ws_size >= WH_BYTES + IITH_BYTES + vox_all) ? 1 : 4;
    int cpos = POS_TOTAL / nch;
    for (int cidx = 0; cidx < nch; ++cidx) {
        int pb = cidx * cpos;
        k_sample<<<cpos / MS, 256, 0, stream>>>(iith, gtl, gbr, voxf, pb);
        k_gemm  <<<(cpos / 128) * 2, 256, 0, stream>>>(voxf, wh, bias, ortho, pb);
    }
}

// Round 17
// 171.434 us; speedup vs baseline: 1.0356x; 1.0241x over previous
//
#include <hip/hip_runtime.h>
#include <hip/hip_fp16.h>

typedef unsigned short ushort_t;
typedef __attribute__((ext_vector_type(8))) _Float16 f16x8;
typedef __attribute__((ext_vector_type(2))) _Float16 f16v2;
typedef __attribute__((ext_vector_type(2))) __fp16 hw16x2;
typedef __attribute__((ext_vector_type(4))) float f32x4;

#define BB   2
#define CCH  256
#define HF   96
#define WF   320
#define NYC  7
#define DWT  16384
#define PLANE (HF*WF)          // 30720
#define KDIM (CCH*NYC)         // 1792
#define NKT  56                // K tiles of 32 (k = y*256 + c)
#define MS   8                 // positions per sample block
#define POS_TOTAL (BB*DWT)     // 32768

#define WH_BYTES   ((size_t)16*NKT*64*8*2)          // 917504
#define IITH_BYTES ((size_t)BB*PLANE*CCH*2)         // 31457280

// ---------------- K1: fused integral image, split column scan ---------------
__global__ __launch_bounds__(640)
void k_integral(const float* __restrict__ f, float* __restrict__ ii) {
    __shared__ float pl[PLANE];            // 122880 B
    __shared__ float tot[WF];              // 1280 B
    int bc = blockIdx.x;
    const float* src = f  + (size_t)bc * PLANE;
    float*       dst = ii + (size_t)bc * PLANE;
    int t = threadIdx.x;

    #pragma unroll
    for (int i = 0; i < PLANE / 4 / 640; ++i) {      // 12 iters exact
        int idx = t + i * 640;
        reinterpret_cast<float4*>(pl)[idx] = reinterpret_cast<const float4*>(src)[idx];
    }
    __syncthreads();

    int lane = t & 63, wv = t >> 6;                  // 10 waves
    for (int rr = wv; rr < HF; rr += 10) {
        float* row = &pl[rr * WF];
        float v0 = row[lane * 5 + 0];
        float v1 = row[lane * 5 + 1];
        float v2 = row[lane * 5 + 2];
        float v3 = row[lane * 5 + 3];
        float v4 = row[lane * 5 + 4];
        v1 += v0; v2 += v1; v3 += v2; v4 += v3;
        float s = v4;
        #pragma unroll
        for (int d = 1; d < 64; d <<= 1) {
            float o = __shfl_up(s, d);
            if (lane >= d) s += o;
        }
        float pre = s - v4;
        row[lane * 5 + 0] = v0 + pre;
        row[lane * 5 + 1] = v1 + pre;
        row[lane * 5 + 2] = v2 + pre;
        row[lane * 5 + 3] = v3 + pre;
        row[lane * 5 + 4] = v4 + pre;
    }
    __syncthreads();

    bool lower = t < WF;
    int x = lower ? t : t - WF;
    float loc[48];
    if (lower) {
        float acc = 0.f;
        #pragma unroll 4
        for (int y = 0; y < 48; ++y) {
            acc += pl[y * WF + x];
            dst[(size_t)y * WF + x] = acc;
        }
        tot[x] = acc;
    } else {
        float acc = 0.f;
        #pragma unroll
        for (int y = 0; y < 48; ++y) {
            acc += pl[(48 + y) * WF + x];
            loc[y] = acc;
        }
    }
    __syncthreads();
    if (!lower) {
        float base = tot[x];
        #pragma unroll
        for (int y = 0; y < 48; ++y)
            dst[(size_t)(48 + y) * WF + x] = loc[y] + base;
    }
}

// ---------------- K2: transpose ii (B,C,H,W) f32 -> iith (B,H,W,C) fp16 ------
__global__ void k_transpose(const float* __restrict__ ii, _Float16* __restrict__ iith) {
    __shared__ float tile[32][33];
    int x0 = blockIdx.x * 32;
    int c0 = blockIdx.y * 32;
    int by = blockIdx.z;               // b*HF + y
    int b  = by / HF;
    int y  = by % HF;
    const float* src = ii + (size_t)b * CCH * PLANE + (size_t)y * WF;
    unsigned* dstu = reinterpret_cast<unsigned*>(iith + (size_t)by * WF * CCH);
    int tx = threadIdx.x;
    int ty = threadIdx.y;
    #pragma unroll
    for (int i = 0; i < 4; ++i) {
        int c = c0 + ty + 8 * i;
        tile[ty + 8 * i][tx] = src[(size_t)c * PLANE + x0 + tx];
    }
    __syncthreads();
    int id = ty * 32 + tx;
    #pragma unroll
    for (int it = 0; it < 2; ++it) {
        int idx = it * 256 + id;
        int xl = idx >> 4;
        int j  = idx & 15;
        float f0 = tile[2 * j][xl];
        float f1 = tile[2 * j + 1][xl];
        __half2 hh = __floats2half2_rn(f0, f1);
        dstu[((size_t)(x0 + xl) * CCH + c0) / 2 + j] = *reinterpret_cast<unsigned*>(&hh);
    }
}

// ---------------- K3: geometry -> g_tl, g_br, g_tr, g_bl ----------------
__global__ void k_geom(const float* __restrict__ calib, const float* __restrict__ grid,
                       float* __restrict__ gtl, float* __restrict__ gbr,
                       float* __restrict__ gtr, float* __restrict__ gbl) {
    int t = blockIdx.x * blockDim.x + threadIdx.x;
    if (t >= BB * NYC * DWT) return;
    int dw = t % DWT;
    int by = t / DWT;
    int y  = by % NYC;
    int b  = by / NYC;
    int d  = dw >> 7;
    int w  = dw & 127;
    const float* cb = calib + b * 12;

    float c0=cb[0],c1=cb[1],c2=cb[2],c3=cb[3];
    float c4=cb[4],c5=cb[5],c6=cb[6],c7=cb[7];
    float c8=cb[8],c9=cb[9],c10=cb[10],c11=cb[11];

    auto ncp = [&](int yy, int i, int j, float& ox, float& oy) {
        const float* g = grid + (((size_t)b * 129 + i) * 129 + j) * 3;
        float gx = g[0];
        float gy = g[1] + (0.5f * (float)yy - 2.0f);
        float gz = g[2];
        float h0 = c0*gx + c1*gy + c2*gz + c3;
        float h1 = c4*gx + c5*gy + c6*gz + c7;
        float h2 = c8*gx + c9*gy + c10*gz + c11;
        float ix = h0 / h2;
        float iy = h1 / h2;
        float nx = 2.0f * ix / ((float)WF / 0.125f) - 1.0f;
        float ny = 2.0f * iy / ((float)HF / 0.125f) - 1.0f;
        ox = fminf(fmaxf(nx, -1.f), 1.f);
        oy = fminf(fmaxf(ny, -1.f), 1.f);
    };

    float ax, ay, bx, byy, mx1, my1, mx2, my2;
    ncp(y,     d,     w,     ax,  ay);
    ncp(y,     d + 1, w,     bx,  byy);
    float minx = fminf(ax, bx), miny = fminf(ay, byy);
    ncp(y + 1, d + 1, w + 1, mx1, my1);
    ncp(y + 1, d,     w + 1, mx2, my2);
    float maxx = fmaxf(mx1, mx2), maxy = fmaxf(my1, my2);

    size_t o = (size_t)t * 2;
    gtl[o] = minx; gtl[o + 1] = miny;
    gbr[o] = maxx; gbr[o + 1] = maxy;
    gtr[o] = maxx; gtr[o + 1] = miny;
    gbl[o] = minx; gbl[o + 1] = maxy;
}

// ---------------- K4: prepack w -> fragment-linear f16 (k = y*256 + c) -------
__global__ void k_prepack(const float* __restrict__ w, _Float16* __restrict__ wh) {
    int t = blockIdx.x * blockDim.x + threadIdx.x;
    if (t >= 16 * NKT * 64) return;
    int lane = t & 63;
    int kt   = (t >> 6) % NKT;
    int nt   = t / (NKT * 64);
    int r = lane & 15, g = lane >> 4;
    const float* wr = w + (size_t)(nt * 16 + r) * KDIM;
    _Float16* dst = wh + (size_t)t * 8;
    #pragma unroll
    for (int j = 0; j < 8; ++j) {
        int k  = kt * 32 + g * 8 + j;
        int yy = k >> 8;
        int cc = k & 255;
        dst[j] = (_Float16)wr[cc * NYC + yy];
    }
}

// ---------------- K5: pure gather -> vox fragments (f16, degenerate skip) ----
// thread: p = t>>5 (8 positions/block), c = (t&31)*8 (channel octet)
__global__ __launch_bounds__(256, 4)
void k_sample(const _Float16* __restrict__ iith, const float* __restrict__ gtl,
              const float* __restrict__ gbr, _Float16* __restrict__ voxf, int pos_base) {
    __shared__ int2 taps[MS][NYC][17];       // 17-pad
    __shared__ float inv_s[MS][NYC + 1];
    int t = threadIdx.x;
    int bid = blockIdx.x;
    int cpx = gridDim.x >> 3;
    int swz = (bid & 7) * cpx + (bid >> 3);  // XCD-chunked (grid % 8 == 0)
    int lpos0 = swz * MS;
    int pos0  = pos_base + lpos0;
    int b   = pos0 / DWT;
    int dw0 = pos0 % DWT;

    if (t < MS * NYC) {
        int p = t / NYC, y = t % NYC;
        size_t gi = (((size_t)(b * NYC + y)) * DWT + dw0 + p) * 2;
        float g0 = gtl[gi], g1 = gtl[gi + 1];
        float g2 = gbr[gi], g3 = gbr[gi + 1];
        float area = (g2 - g0) * (g3 - g1) * ((float)HF * (float)WF * 0.25f) + 1e-6f;
        inv_s[p][y] = (area > 1e-6f) ? (1.0f / area) : 0.0f;
        const float sgn[4] = {1.f, 1.f, -1.f, -1.f};
        float px[4] = {g0, g2, g2, g0};
        float py[4] = {g1, g3, g1, g3};
        #pragma unroll
        for (int q = 0; q < 4; ++q) {
            float x  = (px[q] + 1.0f) * ((float)WF * 0.5f) - 0.5f;
            float yy = (py[q] + 1.0f) * ((float)HF * 0.5f) - 0.5f;
            float x0f = floorf(x), y0f = floorf(yy);
            float wx = x - x0f, wy = yy - y0f;
            float wq[4] = {(1.f-wx)*(1.f-wy), wx*(1.f-wy), (1.f-wx)*wy, wx*wy};
            #pragma unroll
            for (int s = 0; s < 4; ++s) {
                float xi = x0f + (float)(s & 1);
                float yi = y0f + (float)(s >> 1);
                bool valid = (xi >= 0.f) && (xi < (float)WF) && (yi >= 0.f) && (yi < (float)HF);
                int xc = (int)fminf(fmaxf(xi, 0.f), (float)(WF - 1));
                int yc = (int)fminf(fmaxf(yi, 0.f), (float)(HF - 1));
                float wgt = valid ? (wq[s] * sgn[q]) : 0.0f;
                hw16x2 hw = __builtin_amdgcn_cvt_pkrtz(wgt, wgt);
                taps[p][y][q * 4 + s] =
                    make_int2((yc * WF + xc) * CCH, *reinterpret_cast<int*>(&hw));
            }
        }
    }
    __syncthreads();

    int p = t >> 5;
    int c = (t & 31) * 8;
    int lpos = lpos0 + p;
    int mt = lpos >> 4, r = lpos & 15, g = (c >> 3) & 3;
    const _Float16* base = iith + (size_t)b * PLANE * CCH + c;
    _Float16* vbase = voxf + ((size_t)mt * NKT * 64 + (size_t)(g * 16 + r)) * 8;

    for (int y = 0; y < NYC; ++y) {
        float inv = inv_s[p][y];
        int kt = (y << 3) + (c >> 5);
        if (inv == 0.0f) {
            // degenerate box (area<=EPS): vox is exactly 0 -> skip 16 loads
            f16x8 z = {};
            *reinterpret_cast<f16x8*>(vbase + (size_t)kt * 64 * 8) = z;
            continue;
        }

        int2 tp[16];
        #pragma unroll
        for (int q = 0; q < 16; ++q) tp[q] = taps[p][y][q];

        uint4 hv[16];
        #pragma unroll
        for (int q = 0; q < 16; ++q)
            hv[q] = *reinterpret_cast<const uint4*>(base + tp[q].x);
        __builtin_amdgcn_sched_barrier(0);

        f16v2 a0 = {0, 0}, a1 = {0, 0}, a2 = {0, 0}, a3 = {0, 0};
        #pragma unroll
        for (int q = 0; q < 16; ++q) {
            f16v2 w2 = *reinterpret_cast<f16v2*>(&tp[q].y);
            a0 += w2 * *reinterpret_cast<f16v2*>(&hv[q].x);
            a1 += w2 * *reinterpret_cast<f16v2*>(&hv[q].y);
            a2 += w2 * *reinterpret_cast<f16v2*>(&hv[q].z);
            a3 += w2 * *reinterpret_cast<f16v2*>(&hv[q].w);
        }
        hw16x2 ivh = __builtin_amdgcn_cvt_pkrtz(inv, inv);
        f16v2 iv2 = *reinterpret_cast<f16v2*>(&ivh);
        a0 *= iv2; a1 *= iv2; a2 *= iv2; a3 *= iv2;

        f16x8 o;
        o[0] = a0[0]; o[1] = a0[1]; o[2] = a1[0]; o[3] = a1[1];
        o[4] = a2[0]; o[5] = a2[1]; o[6] = a3[0]; o[7] = a3[1];
        // normal cached store (r10: nontemporal doubles HBM writes)
        *reinterpret_cast<f16x8*>(vbase + (size_t)kt * 64 * 8) = o;
    }
}

// ---------------- K6: register-blocked MFMA GEMM, depth-4 prefetch -----------
__global__ __launch_bounds__(256, 2)
void k_gemm(const _Float16* __restrict__ voxf, const _Float16* __restrict__ wh,
            const float* __restrict__ bias, float* __restrict__ ortho, int pos_base) {
    int t = threadIdx.x;
    int lane = t & 63, wv = t >> 6;
    int mi = wv >> 1, ni = wv & 1;
    int bx = blockIdx.x;
    int swz = (bx & 7) * (gridDim.x >> 3) + (bx >> 3);   // XCD-chunked
    int nhalf = swz & 1, pm = swz >> 1;
    int lpos0 = pm * 128;
    int pos0 = pos_base + lpos0;
    int b = pos0 / DWT, dw0 = pos0 % DWT;
    int mt0 = (lpos0 >> 4) + mi * 4;
    int nt0 = nhalf * 8 + ni * 4;

    const f16x8* ap = reinterpret_cast<const f16x8*>(voxf) + (size_t)mt0 * NKT * 64 + lane;
    const f16x8* bp = reinterpret_cast<const f16x8*>(wh)   + (size_t)nt0 * NKT * 64 + lane;
    const size_t TS = (size_t)NKT * 64;     // tile stride in f16x8

    f32x4 acc[4][4] = {};
    f16x8 A0[4], A1[4], A2[4], A3[4];
    f16x8 B0[4], B1[4], B2[4], B3[4];
    #pragma unroll
    for (int i = 0; i < 4; ++i) {
        A0[i] = ap[i * TS];            B0[i] = bp[i * TS];
        A1[i] = ap[i * TS + 64];       B1[i] = bp[i * TS + 64];
        A2[i] = ap[i * TS + 128];      B2[i] = bp[i * TS + 128];
        A3[i] = ap[i * TS + 192];      B3[i] = bp[i * TS + 192];
    }

#define GSTEP(AJ, BJ, J)                                                        \
    {                                                                           \
        _Pragma("unroll")                                                       \
        for (int m = 0; m < 4; ++m)                                             \
            _Pragma("unroll")                                                   \
            for (int n = 0; n < 4; ++n)                                         \
                acc[m][n] = __builtin_amdgcn_mfma_f32_16x16x32_f16(AJ[m], BJ[n], acc[m][n], 0, 0, 0); \
        int kp = kt + 4 + J; if (kp > NKT - 1) kp = NKT - 1;                    \
        _Pragma("unroll")                                                       \
        for (int i = 0; i < 4; ++i) {                                           \
            AJ[i] = ap[i * TS + (size_t)kp * 64];                               \
            BJ[i] = bp[i * TS + (size_t)kp * 64];                               \
        }                                                                       \
    }

    for (int kt = 0; kt < NKT; kt += 4) {
        GSTEP(A0, B0, 0)
        GSTEP(A1, B1, 1)
        GSTEP(A2, B2, 2)
        GSTEP(A3, B3, 3)
    }
#undef GSTEP

    int r = lane & 15, gq = lane >> 4;
    #pragma unroll
    for (int n = 0; n < 4; ++n) {
        int co = nhalf * 128 + (ni * 4 + n) * 16 + r;
        float bv = bias[co];
        float* ob = ortho + ((size_t)(b * CCH + co)) * DWT + dw0 + gq * 4;
        #pragma unroll
        for (int m = 0; m < 4; ++m) {
            float4 o = make_float4(fmaxf(acc[m][n][0] + bv, 0.f), fmaxf(acc[m][n][1] + bv, 0.f),
                                   fmaxf(acc[m][n][2] + bv, 0.f), fmaxf(acc[m][n][3] + bv, 0.f));
            *reinterpret_cast<float4*>(ob + (mi * 4 + m) * 16) = o;
        }
    }
}

extern "C" void kernel_launch(void* const* d_in, const int* in_sizes, int n_in,
                              void* d_out, int out_size, void* d_ws, size_t ws_size,
                              hipStream_t stream) {
    const float* features = (const float*)d_in[0];
    const float* calib    = (const float*)d_in[1];
    const float* grid     = (const float*)d_in[2];
    const float* w        = (const float*)d_in[3];
    const float* bias     = (const float*)d_in[4];

    float* out   = (float*)d_out;
    float* ortho = out;
    float* ii    = out + (size_t)8388608;
    float* gtl   = out + (size_t)24117248;
    float* gbr   = out + (size_t)24576000;
    float* gtr   = out + (size_t)25034752;
    float* gbl   = out + (size_t)25493504;

    _Float16* wh   = (_Float16*)d_ws;
    _Float16* iith = (_Float16*)((char*)d_ws + WH_BYTES);
    _Float16* voxf = (_Float16*)((char*)d_ws + WH_BYTES + IITH_BYTES);

    k_integral<<<BB * CCH, 640, 0, stream>>>(features, ii);
    k_geom    <<<(BB * NYC * DWT + 255) / 256, 256, 0, stream>>>(calib, grid, gtl, gbr, gtr, gbl);
    k_prepack <<<(16 * NKT * 64 + 255) / 256, 256, 0, stream>>>(w, wh);
    dim3 gT(WF / 32, CCH / 32, BB * HF);
    k_transpose<<<gT, dim3(32, 8), 0, stream>>>(ii, iith);

    // nch=1 when ws fits the full vox (117 MB)
    size_t vox_all = (size_t)POS_TOTAL * KDIM * 2;
    int nch = (ws_size >= WH_BYTES + IITH_BYTES + vox_all) ? 1 : 4;
    int cpos = POS_TOTAL / nch;
    for (int cidx = 0; cidx < nch; ++cidx) {
        int pb = cidx * cpos;
        k_sample<<<cpos / MS, 256, 0, stream>>>(iith, gtl, gbr, voxf, pb);
        k_gemm  <<<(cpos / 128) * 2, 256, 0, stream>>>(voxf, wh, bias, ortho, pb);
    }
}